// Round 4
// baseline (337.133 us; speedup 1.0000x reference)
//
#include <hip/hip_runtime.h>
#include <math.h>

#define NB 8
#define NH 8
#define NS 1024
#define NE 512
#define NA 64
#define NBH (NB*NH)

typedef short s8v __attribute__((ext_vector_type(8)));   // 8 bf16 (4 VGPRs)
typedef float f4v __attribute__((ext_vector_type(4)));   // 4 f32 accum

#define MFMA16(a,b,c) __builtin_amdgcn_mfma_f32_16x16x32_bf16((a),(b),(c),0,0,0)

static __device__ __forceinline__ unsigned short f2bf(float f) {
    union { float f; unsigned u; } c; c.f = f;
    unsigned r = c.u + 0x7FFF + ((c.u >> 16) & 1);   // RNE
    return (unsigned short)(r >> 16);
}
static __device__ __forceinline__ s8v ld8(const unsigned short* p) {
    return *(const s8v*)p;
}
static __device__ __forceinline__ void gload16(const unsigned short* g, unsigned short* l) {
    __builtin_amdgcn_global_load_lds(
        (const __attribute__((address_space(1))) unsigned char*)g,
        (__attribute__((address_space(3))) unsigned char*)l, 16, 0, 0);
}

// stage a 128-row x 64-ush tile (row stride `stride` ush) into 16KB of LDS, linear.
static __device__ __forceinline__ void stage_tile(
    const unsigned short* src, size_t stride, int k0,
    unsigned short* lds, int tid)
{
    int w = tid >> 6, l = tid & 63;
    #pragma unroll
    for (int c = 0; c < 4; ++c) {
        int chunk = w * 4 + c;
        int row = chunk * 8 + (l >> 3);
        gload16(src + (size_t)row * stride + k0 + (l & 7) * 8,
                lds + chunk * 512 + l * 8);
    }
}

// ---------------- K1: embedding gather + LayerNorm -> h_bf16 [B*S, E] ----------------
__global__ __launch_bounds__(256) void k_embed_ln(
    const int* __restrict__ x, const float* __restrict__ emb,
    const float* __restrict__ gamma, const float* __restrict__ beta,
    unsigned short* __restrict__ hb)
{
    int row = blockIdx.x;
    int tok = x[row];
    const float* e = emb + (size_t)tok * NE;
    int t = threadIdx.x;
    float v0 = e[t], v1 = e[t + 256];
    float sum = v0 + v1, ssq = v0 * v0 + v1 * v1;
    #pragma unroll
    for (int o = 32; o > 0; o >>= 1) {
        sum += __shfl_xor(sum, o);
        ssq += __shfl_xor(ssq, o);
    }
    __shared__ float wsum[4], wssq[4];
    __shared__ float mu_s, rstd_s;
    int wid = t >> 6;
    if ((t & 63) == 0) { wsum[wid] = sum; wssq[wid] = ssq; }
    __syncthreads();
    if (t == 0) {
        float S1 = wsum[0] + wsum[1] + wsum[2] + wsum[3];
        float S2 = wssq[0] + wssq[1] + wssq[2] + wssq[3];
        float mu = S1 / NE;
        float var = S2 / NE - mu * mu;
        mu_s = mu;
        rstd_s = rsqrtf(var + 1e-5f);
    }
    __syncthreads();
    float mu = mu_s, rstd = rstd_s;
    unsigned short* hr = hb + (size_t)row * NE;
    hr[t]       = f2bf((v0 - mu) * rstd * gamma[t]       + beta[t]);
    hr[t + 256] = f2bf((v1 - mu) * rstd * gamma[t + 256] + beta[t + 256]);
}

// ---------------- f32 -> bf16 convert ----------------
__global__ __launch_bounds__(256) void k_cvt(
    const float* __restrict__ in, unsigned short* __restrict__ out, int n)
{
    int i = blockIdx.x * 256 + threadIdx.x;
    if (i < n) out[i] = f2bf(in[i]);
}

// ---------------- K2: Q/K projection, LDS-staged GEMM ----------------
__global__ __launch_bounds__(256) void k_qk_gemm(
    const unsigned short* __restrict__ hb, const unsigned short* __restrict__ wqb,
    const unsigned short* __restrict__ wkb,
    unsigned short* __restrict__ qb, unsigned short* __restrict__ kbf)
{
    int bid = blockIdx.x;
    int b2 = (bid & 7) * 64 + (bid >> 3);
    int st = b2 & 7, bh = b2 >> 3;
    int b = bh >> 3, hh = bh & 7;
    int tid = threadIdx.x;
    int w = tid >> 6, l = tid & 63;
    int lo = l & 15, hi = l >> 4;
    int wr = w >> 1, wc = w & 1;

    __shared__ __align__(16) unsigned short As[128 * 64];
    __shared__ __align__(16) unsigned short Bs[128 * 64];

    f4v acc[4][4];
    f4v z = {0.f, 0.f, 0.f, 0.f};
    #pragma unroll
    for (int i = 0; i < 4; ++i)
        #pragma unroll
        for (int j = 0; j < 4; ++j) acc[i][j] = z;

    const unsigned short* asrc = hb + ((size_t)(b * NS) + st * 128) * NE;
    for (int kt = 0; kt < 8; ++kt) {
        int k0 = kt * 64;
        stage_tile(asrc, NE, k0, As, tid);
        {
            #pragma unroll
            for (int c = 0; c < 4; ++c) {
                int chunk = w * 4 + c;
                int row = chunk * 8 + (l >> 3);
                const unsigned short* bsrc = (chunk < 8)
                    ? wqb + ((size_t)(hh * NA) + row) * NE
                    : wkb + ((size_t)(hh * NA) + row - 64) * NE;
                gload16(bsrc + k0 + (l & 7) * 8, Bs + chunk * 512 + l * 8);
            }
        }
        __syncthreads();
        #pragma unroll
        for (int ks = 0; ks < 2; ++ks) {
            s8v af[4], bf[4];
            #pragma unroll
            for (int sub = 0; sub < 4; ++sub)
                af[sub] = ld8(As + (wr * 64 + sub * 16 + lo) * 64 + ks * 32 + hi * 8);
            #pragma unroll
            for (int es = 0; es < 4; ++es)
                bf[es] = ld8(Bs + (wc * 64 + es * 16 + lo) * 64 + ks * 32 + hi * 8);
            #pragma unroll
            for (int sub = 0; sub < 4; ++sub)
                #pragma unroll
                for (int es = 0; es < 4; ++es)
                    acc[sub][es] = MFMA16(af[sub], bf[es], acc[sub][es]);
        }
        __syncthreads();
    }
    unsigned short* dst = (wc == 0) ? qb : kbf;
    #pragma unroll
    for (int sub = 0; sub < 4; ++sub)
        #pragma unroll
        for (int es = 0; es < 4; ++es)
            #pragma unroll
            for (int i = 0; i < 4; ++i) {
                int s = st * 128 + wr * 64 + sub * 16 + hi * 4 + i;
                int a = es * 16 + lo;
                dst[((size_t)bh * NS + s) * NA + a] = f2bf(acc[sub][es][i]);
            }
}

// ---------------- K3: V projection, LDS-staged GEMM -> vT bf16 [bh][e'][t] ----------------
__global__ __launch_bounds__(256) void k_v_gemm(
    const unsigned short* __restrict__ hb, const unsigned short* __restrict__ wvb,
    unsigned short* __restrict__ vtb)
{
    int bid = blockIdx.x;
    int b2 = (bid & 7) * 256 + (bid >> 3);
    int tt = b2 & 7;
    int et = (b2 >> 3) & 3;
    int bh = b2 >> 5;
    int b = bh >> 3, hh = bh & 7;
    int tid = threadIdx.x;
    int w = tid >> 6, l = tid & 63;
    int lo = l & 15, hi = l >> 4;
    int wr = w >> 1, wc = w & 1;

    __shared__ __align__(16) unsigned short As[128 * 64];
    __shared__ __align__(16) unsigned short Bs[128 * 64];

    f4v acc[4][4];
    f4v z = {0.f, 0.f, 0.f, 0.f};
    #pragma unroll
    for (int i = 0; i < 4; ++i)
        #pragma unroll
        for (int j = 0; j < 4; ++j) acc[i][j] = z;

    const unsigned short* asrc = wvb + ((size_t)(hh * NE) + et * 128) * NE;
    const unsigned short* bsrc = hb + ((size_t)(b * NS) + tt * 128) * NE;
    for (int kt = 0; kt < 8; ++kt) {
        int k0 = kt * 64;
        stage_tile(asrc, NE, k0, As, tid);
        stage_tile(bsrc, NE, k0, Bs, tid);
        __syncthreads();
        #pragma unroll
        for (int ks = 0; ks < 2; ++ks) {
            s8v af[4], bf[4];
            #pragma unroll
            for (int sub = 0; sub < 4; ++sub)
                af[sub] = ld8(As + (wr * 64 + sub * 16 + lo) * 64 + ks * 32 + hi * 8);
            #pragma unroll
            for (int es = 0; es < 4; ++es)
                bf[es] = ld8(Bs + (wc * 64 + es * 16 + lo) * 64 + ks * 32 + hi * 8);
            #pragma unroll
            for (int sub = 0; sub < 4; ++sub)
                #pragma unroll
                for (int es = 0; es < 4; ++es)
                    acc[sub][es] = MFMA16(af[sub], bf[es], acc[sub][es]);
        }
        __syncthreads();
    }
    #pragma unroll
    for (int sub = 0; sub < 4; ++sub)
        #pragma unroll
        for (int es = 0; es < 4; ++es)
            #pragma unroll
            for (int i = 0; i < 4; ++i) {
                int e_ = et * 128 + wr * 64 + sub * 16 + hi * 4 + i;
                int t_ = tt * 128 + wc * 64 + es * 16 + lo;
                vtb[((size_t)bh * NE + e_) * NS + t_] = f2bf(acc[sub][es][i]);
            }
}

// ---------------- K4: per-row min/max of QK^T, LDS-staged K ----------------
__global__ __launch_bounds__(256) void k_minmax_mfma(
    const unsigned short* __restrict__ qb, const unsigned short* __restrict__ kbf,
    float* __restrict__ rmn, float* __restrict__ rmx)
{
    int bid = blockIdx.x;
    int b2 = (bid & 7) * 128 + (bid >> 3);
    int qt = b2 & 15, bh = b2 >> 4;
    int tid = threadIdx.x;
    int w = tid >> 6, l = tid & 63;
    int lo = l & 15, hi = l >> 4;
    int s0 = qt * 64 + w * 16;

    const unsigned short* qp = qb + ((size_t)bh * NS + s0 + lo) * NA + hi * 8;
    s8v a0 = ld8(qp), a1 = ld8(qp + 32);

    __shared__ __align__(16) unsigned short Ks[128 * 64];

    f4v mn4 = {1e30f, 1e30f, 1e30f, 1e30f};
    f4v mx4 = {-1e30f, -1e30f, -1e30f, -1e30f};
    const unsigned short* ksrc = kbf + (size_t)bh * NS * NA;
    for (int t0 = 0; t0 < NS; t0 += 128) {
        __syncthreads();
        stage_tile(ksrc + (size_t)t0 * NA, NA, 0, Ks, tid);
        __syncthreads();
        #pragma unroll
        for (int tf = 0; tf < 8; ++tf) {
            s8v b0 = ld8(Ks + (tf * 16 + lo) * 64 + hi * 8);
            s8v b1 = ld8(Ks + (tf * 16 + lo) * 64 + 32 + hi * 8);
            f4v c = {0.f, 0.f, 0.f, 0.f};
            c = MFMA16(a0, b0, c);
            c = MFMA16(a1, b1, c);
            #pragma unroll
            for (int i = 0; i < 4; ++i) {
                mn4[i] = fminf(mn4[i], c[i]);
                mx4[i] = fmaxf(mx4[i], c[i]);
            }
        }
    }
    #pragma unroll
    for (int i = 0; i < 4; ++i) {
        float m = mn4[i], M = mx4[i];
        #pragma unroll
        for (int off = 1; off < 16; off <<= 1) {
            m = fminf(m, __shfl_xor(m, off));
            M = fmaxf(M, __shfl_xor(M, off));
        }
        if (lo == 0) {
            rmn[(size_t)bh * NS + s0 + hi * 4 + i] = m;
            rmx[(size_t)bh * NS + s0 + hi * 4 + i] = M;
        }
    }
}

// ---------------- K5: scores -> sigmoid weights -> PV ----------------
// double-buffered wt; one barrier per t-tile; fma+exp2+rcp sigmoid.
#define WSTR 136
__global__ __launch_bounds__(512, 2) void k_attn_mfma(
    const unsigned short* __restrict__ qb, const unsigned short* __restrict__ kbf,
    const unsigned short* __restrict__ vtb, const float* __restrict__ rmn,
    const float* __restrict__ rmx, float* __restrict__ out)
{
    int bid = blockIdx.x;
    int b2 = (bid & 7) * 128 + (bid >> 3);
    int qt = b2 & 15, bh = b2 >> 4;
    int s0 = qt * 64;
    int tid = threadIdx.x;
    int w = tid >> 6, l = tid & 63;
    int lo = l & 15, hi = l >> 4;

    __shared__ unsigned short wt[2][64 * WSTR];   // 34816 B

    // sigmoid row coefficients: sn = fma(c, inv, n2)
    float invv[4][4], n2v[4][4];
    #pragma unroll
    for (int sub = 0; sub < 4; ++sub)
        #pragma unroll
        for (int i = 0; i < 4; ++i) {
            int r = s0 + sub * 16 + hi * 4 + i;
            float mn = rmn[(size_t)bh * NS + r];
            float iv = __builtin_amdgcn_rcpf(rmx[(size_t)bh * NS + r] - mn);
            invv[sub][i] = iv;
            n2v[sub][i] = -mn * iv;
        }

    const unsigned short* qbase = qb + ((size_t)bh * NS + s0) * NA;
    const unsigned short* kbase = kbf + (size_t)bh * NS * NA;
    const unsigned short* vbase = vtb + ((size_t)bh * NE + w * 64) * NS;

    f4v acc[4][4];
    f4v z = {0.f, 0.f, 0.f, 0.f};
    #pragma unroll
    for (int sub = 0; sub < 4; ++sub)
        #pragma unroll
        for (int es = 0; es < 4; ++es) acc[sub][es] = z;

    // scores for t-tile `t0` -> wbuf (wave w owns cols t0+w*16 .. +16)
    auto compute_scores = [&](int t0, unsigned short* wbuf) {
        const unsigned short* kp = kbase + ((size_t)(t0 + w * 16 + lo)) * NA + hi * 8;
        s8v kb0 = ld8(kp), kb1 = ld8(kp + 32);
        #pragma unroll
        for (int sub = 0; sub < 4; ++sub) {
            const unsigned short* qp = qbase + ((size_t)(sub * 16 + lo)) * NA + hi * 8;
            f4v c = z;
            c = MFMA16(ld8(qp), kb0, c);
            c = MFMA16(ld8(qp + 32), kb1, c);
            #pragma unroll
            for (int i = 0; i < 4; ++i) {
                float sn = fmaf(c[i], invv[sub][i], n2v[sub][i]);
                float arg = fmaf(sn, -14.4269504089f, 7.2134752044f); // (5-10sn)*log2e
                float e = __builtin_amdgcn_exp2f(arg);
                float wv = __builtin_amdgcn_rcpf(1.f + e);
                wbuf[(sub * 16 + hi * 4 + i) * WSTR + w * 16 + lo] = f2bf(wv);
            }
        }
    };

    auto pv_accum = [&](int t0, const unsigned short* wbuf) {
        #pragma unroll
        for (int ks = 0; ks < 4; ++ks) {
            s8v aw[4];
            #pragma unroll
            for (int sub = 0; sub < 4; ++sub)
                aw[sub] = *(const s8v*)(wbuf + (sub * 16 + lo) * WSTR + ks * 32 + hi * 8);
            #pragma unroll
            for (int es = 0; es < 4; ++es) {
                s8v bv = ld8(vbase + ((size_t)(es * 16 + lo)) * NS + t0 + ks * 32 + hi * 8);
                #pragma unroll
                for (int sub = 0; sub < 4; ++sub)
                    acc[sub][es] = MFMA16(aw[sub], bv, acc[sub][es]);
            }
        }
    };

    compute_scores(0, wt[0]);
    __syncthreads();
    #pragma unroll
    for (int it = 0; it < 8; ++it) {
        if (it < 7) compute_scores((it + 1) * 128, wt[(it + 1) & 1]);
        pv_accum(it * 128, wt[it & 1]);
        if (it < 7) __syncthreads();
    }

    #pragma unroll
    for (int sub = 0; sub < 4; ++sub)
        #pragma unroll
        for (int es = 0; es < 4; ++es)
            #pragma unroll
            for (int i = 0; i < 4; ++i)
                out[((size_t)bh * NS + s0 + sub * 16 + hi * 4 + i) * NE
                    + w * 64 + es * 16 + lo] = acc[sub][es][i];
}

extern "C" void kernel_launch(void* const* d_in, const int* in_sizes, int n_in,
                              void* d_out, int out_size, void* d_ws, size_t ws_size,
                              hipStream_t stream) {
    const int*   x     = (const int*)d_in[0];
    const float* emb   = (const float*)d_in[1];
    const float* gamma = (const float*)d_in[2];
    const float* beta  = (const float*)d_in[3];
    const float* Wq    = (const float*)d_in[4];
    const float* Wk    = (const float*)d_in[5];
    const float* Wv    = (const float*)d_in[6];
    float* out = (float*)d_out;

    unsigned short* p = (unsigned short*)d_ws;
    unsigned short* hb  = p;  p += (size_t)NB * NS * NE;
    unsigned short* qb  = p;  p += (size_t)NBH * NS * NA;
    unsigned short* kb  = p;  p += (size_t)NBH * NS * NA;
    unsigned short* vtb = p;  p += (size_t)NBH * NS * NE;
    unsigned short* wqb = p;  p += (size_t)NH * NA * NE;
    unsigned short* wkb = p;  p += (size_t)NH * NA * NE;
    unsigned short* wvb = p;  p += (size_t)NH * NE * NE;
    float* rmn = (float*)p;
    float* rmx = rmn + (size_t)NBH * NS;

    const int nqk = NH * NA * NE, nv = NH * NE * NE;
    k_cvt<<<(nqk + 255) / 256, 256, 0, stream>>>(Wq, wqb, nqk);
    k_cvt<<<(nqk + 255) / 256, 256, 0, stream>>>(Wk, wkb, nqk);
    k_cvt<<<(nv + 255) / 256, 256, 0, stream>>>(Wv, wvb, nv);
    k_embed_ln<<<NB * NS, 256, 0, stream>>>(x, emb, gamma, beta, hb);
    k_qk_gemm<<<512, 256, 0, stream>>>(hb, wqb, wkb, qb, kb);
    k_v_gemm<<<2048, 256, 0, stream>>>(hb, wvb, vtb);
    k_minmax_mfma<<<1024, 256, 0, stream>>>(qb, kb, rmn, rmx);
    k_attn_mfma<<<1024, 512, 0, stream>>>(qb, kb, vtb, rmn, rmx, out);
}

// Round 6
// 293.022 us; speedup vs baseline: 1.1505x; 1.1505x over previous
//
#include <hip/hip_runtime.h>
#include <math.h>

#define NB 8
#define NH 8
#define NS 1024
#define NE 512
#define NA 64
#define NBH (NB*NH)

typedef short s8v __attribute__((ext_vector_type(8)));   // 8 bf16 (4 VGPRs)
typedef float f4v __attribute__((ext_vector_type(4)));   // 4 f32 accum

#define MFMA16(a,b,c) __builtin_amdgcn_mfma_f32_16x16x32_bf16((a),(b),(c),0,0,0)

static __device__ __forceinline__ unsigned short f2bf(float f) {
    union { float f; unsigned u; } c; c.f = f;
    unsigned r = c.u + 0x7FFF + ((c.u >> 16) & 1);   // RNE
    return (unsigned short)(r >> 16);
}
static __device__ __forceinline__ s8v ld8(const unsigned short* p) {
    return *(const s8v*)p;
}
static __device__ __forceinline__ void gload16(const unsigned short* g, unsigned short* l) {
    __builtin_amdgcn_global_load_lds(
        (const __attribute__((address_space(1))) unsigned char*)g,
        (__attribute__((address_space(3))) unsigned char*)l, 16, 0, 0);
}

// stage a 128-row x 64-ush tile (row stride `stride` ush) into 16KB of LDS, linear.
static __device__ __forceinline__ void stage_tile(
    const unsigned short* src, size_t stride, int k0,
    unsigned short* lds, int tid)
{
    int w = tid >> 6, l = tid & 63;
    #pragma unroll
    for (int c = 0; c < 4; ++c) {
        int chunk = w * 4 + c;
        int row = chunk * 8 + (l >> 3);
        gload16(src + (size_t)row * stride + k0 + (l & 7) * 8,
                lds + chunk * 512 + l * 8);
    }
}

// ---------------- K1: embedding gather + LayerNorm -> h_bf16 [B*S, E] ----------------
__global__ __launch_bounds__(256) void k_embed_ln(
    const int* __restrict__ x, const float* __restrict__ emb,
    const float* __restrict__ gamma, const float* __restrict__ beta,
    unsigned short* __restrict__ hb)
{
    int row = blockIdx.x;
    int tok = x[row];
    const float* e = emb + (size_t)tok * NE;
    int t = threadIdx.x;
    float v0 = e[t], v1 = e[t + 256];
    float sum = v0 + v1, ssq = v0 * v0 + v1 * v1;
    #pragma unroll
    for (int o = 32; o > 0; o >>= 1) {
        sum += __shfl_xor(sum, o);
        ssq += __shfl_xor(ssq, o);
    }
    __shared__ float wsum[4], wssq[4];
    __shared__ float mu_s, rstd_s;
    int wid = t >> 6;
    if ((t & 63) == 0) { wsum[wid] = sum; wssq[wid] = ssq; }
    __syncthreads();
    if (t == 0) {
        float S1 = wsum[0] + wsum[1] + wsum[2] + wsum[3];
        float S2 = wssq[0] + wssq[1] + wssq[2] + wssq[3];
        float mu = S1 / NE;
        float var = S2 / NE - mu * mu;
        mu_s = mu;
        rstd_s = rsqrtf(var + 1e-5f);
    }
    __syncthreads();
    float mu = mu_s, rstd = rstd_s;
    unsigned short* hr = hb + (size_t)row * NE;
    hr[t]       = f2bf((v0 - mu) * rstd * gamma[t]       + beta[t]);
    hr[t + 256] = f2bf((v1 - mu) * rstd * gamma[t + 256] + beta[t + 256]);
}

// ---------------- f32 -> bf16 convert ----------------
__global__ __launch_bounds__(256) void k_cvt(
    const float* __restrict__ in, unsigned short* __restrict__ out, int n)
{
    int i = blockIdx.x * 256 + threadIdx.x;
    if (i < n) out[i] = f2bf(in[i]);
}

// ---------------- K2: Q/K projection, LDS-staged GEMM ----------------
__global__ __launch_bounds__(256) void k_qk_gemm(
    const unsigned short* __restrict__ hb, const unsigned short* __restrict__ wqb,
    const unsigned short* __restrict__ wkb,
    unsigned short* __restrict__ qb, unsigned short* __restrict__ kbf)
{
    int bid = blockIdx.x;
    int b2 = (bid & 7) * 64 + (bid >> 3);
    int st = b2 & 7, bh = b2 >> 3;
    int b = bh >> 3, hh = bh & 7;
    int tid = threadIdx.x;
    int w = tid >> 6, l = tid & 63;
    int lo = l & 15, hi = l >> 4;
    int wr = w >> 1, wc = w & 1;

    __shared__ __align__(16) unsigned short As[128 * 64];
    __shared__ __align__(16) unsigned short Bs[128 * 64];

    f4v acc[4][4];
    f4v z = {0.f, 0.f, 0.f, 0.f};
    #pragma unroll
    for (int i = 0; i < 4; ++i)
        #pragma unroll
        for (int j = 0; j < 4; ++j) acc[i][j] = z;

    const unsigned short* asrc = hb + ((size_t)(b * NS) + st * 128) * NE;
    for (int kt = 0; kt < 8; ++kt) {
        int k0 = kt * 64;
        stage_tile(asrc, NE, k0, As, tid);
        {
            #pragma unroll
            for (int c = 0; c < 4; ++c) {
                int chunk = w * 4 + c;
                int row = chunk * 8 + (l >> 3);
                const unsigned short* bsrc = (chunk < 8)
                    ? wqb + ((size_t)(hh * NA) + row) * NE
                    : wkb + ((size_t)(hh * NA) + row - 64) * NE;
                gload16(bsrc + k0 + (l & 7) * 8, Bs + chunk * 512 + l * 8);
            }
        }
        __syncthreads();
        #pragma unroll
        for (int ks = 0; ks < 2; ++ks) {
            s8v af[4], bf[4];
            #pragma unroll
            for (int sub = 0; sub < 4; ++sub)
                af[sub] = ld8(As + (wr * 64 + sub * 16 + lo) * 64 + ks * 32 + hi * 8);
            #pragma unroll
            for (int es = 0; es < 4; ++es)
                bf[es] = ld8(Bs + (wc * 64 + es * 16 + lo) * 64 + ks * 32 + hi * 8);
            #pragma unroll
            for (int sub = 0; sub < 4; ++sub)
                #pragma unroll
                for (int es = 0; es < 4; ++es)
                    acc[sub][es] = MFMA16(af[sub], bf[es], acc[sub][es]);
        }
        __syncthreads();
    }
    unsigned short* dst = (wc == 0) ? qb : kbf;
    #pragma unroll
    for (int sub = 0; sub < 4; ++sub)
        #pragma unroll
        for (int es = 0; es < 4; ++es)
            #pragma unroll
            for (int i = 0; i < 4; ++i) {
                int s = st * 128 + wr * 64 + sub * 16 + hi * 4 + i;
                int a = es * 16 + lo;
                dst[((size_t)bh * NS + s) * NA + a] = f2bf(acc[sub][es][i]);
            }
}

// ---------------- K3: V projection, LDS-staged GEMM -> vT bf16 [bh][e'][t] ----------------
__global__ __launch_bounds__(256) void k_v_gemm(
    const unsigned short* __restrict__ hb, const unsigned short* __restrict__ wvb,
    unsigned short* __restrict__ vtb)
{
    int bid = blockIdx.x;
    int b2 = (bid & 7) * 256 + (bid >> 3);
    int tt = b2 & 7;
    int et = (b2 >> 3) & 3;
    int bh = b2 >> 5;
    int b = bh >> 3, hh = bh & 7;
    int tid = threadIdx.x;
    int w = tid >> 6, l = tid & 63;
    int lo = l & 15, hi = l >> 4;
    int wr = w >> 1, wc = w & 1;

    __shared__ __align__(16) unsigned short As[128 * 64];
    __shared__ __align__(16) unsigned short Bs[128 * 64];

    f4v acc[4][4];
    f4v z = {0.f, 0.f, 0.f, 0.f};
    #pragma unroll
    for (int i = 0; i < 4; ++i)
        #pragma unroll
        for (int j = 0; j < 4; ++j) acc[i][j] = z;

    const unsigned short* asrc = wvb + ((size_t)(hh * NE) + et * 128) * NE;
    const unsigned short* bsrc = hb + ((size_t)(b * NS) + tt * 128) * NE;
    for (int kt = 0; kt < 8; ++kt) {
        int k0 = kt * 64;
        stage_tile(asrc, NE, k0, As, tid);
        stage_tile(bsrc, NE, k0, Bs, tid);
        __syncthreads();
        #pragma unroll
        for (int ks = 0; ks < 2; ++ks) {
            s8v af[4], bf[4];
            #pragma unroll
            for (int sub = 0; sub < 4; ++sub)
                af[sub] = ld8(As + (wr * 64 + sub * 16 + lo) * 64 + ks * 32 + hi * 8);
            #pragma unroll
            for (int es = 0; es < 4; ++es)
                bf[es] = ld8(Bs + (wc * 64 + es * 16 + lo) * 64 + ks * 32 + hi * 8);
            #pragma unroll
            for (int sub = 0; sub < 4; ++sub)
                #pragma unroll
                for (int es = 0; es < 4; ++es)
                    acc[sub][es] = MFMA16(af[sub], bf[es], acc[sub][es]);
        }
        __syncthreads();
    }
    #pragma unroll
    for (int sub = 0; sub < 4; ++sub)
        #pragma unroll
        for (int es = 0; es < 4; ++es)
            #pragma unroll
            for (int i = 0; i < 4; ++i) {
                int e_ = et * 128 + wr * 64 + sub * 16 + hi * 4 + i;
                int t_ = tt * 128 + wc * 64 + es * 16 + lo;
                vtb[((size_t)bh * NE + e_) * NS + t_] = f2bf(acc[sub][es][i]);
            }
}

// ---------------- K4: per-row min/max of QK^T, LDS-staged K ----------------
__global__ __launch_bounds__(256) void k_minmax_mfma(
    const unsigned short* __restrict__ qb, const unsigned short* __restrict__ kbf,
    float* __restrict__ rmn, float* __restrict__ rmx)
{
    int bid = blockIdx.x;
    int b2 = (bid & 7) * 128 + (bid >> 3);
    int qt = b2 & 15, bh = b2 >> 4;
    int tid = threadIdx.x;
    int w = tid >> 6, l = tid & 63;
    int lo = l & 15, hi = l >> 4;
    int s0 = qt * 64 + w * 16;

    const unsigned short* qp = qb + ((size_t)bh * NS + s0 + lo) * NA + hi * 8;
    s8v a0 = ld8(qp), a1 = ld8(qp + 32);

    __shared__ __align__(16) unsigned short Ks[128 * 64];

    f4v mn4 = {1e30f, 1e30f, 1e30f, 1e30f};
    f4v mx4 = {-1e30f, -1e30f, -1e30f, -1e30f};
    const unsigned short* ksrc = kbf + (size_t)bh * NS * NA;
    for (int t0 = 0; t0 < NS; t0 += 128) {
        __syncthreads();
        stage_tile(ksrc + (size_t)t0 * NA, NA, 0, Ks, tid);
        __syncthreads();
        #pragma unroll
        for (int tf = 0; tf < 8; ++tf) {
            s8v b0 = ld8(Ks + (tf * 16 + lo) * 64 + hi * 8);
            s8v b1 = ld8(Ks + (tf * 16 + lo) * 64 + 32 + hi * 8);
            f4v c = {0.f, 0.f, 0.f, 0.f};
            c = MFMA16(a0, b0, c);
            c = MFMA16(a1, b1, c);
            #pragma unroll
            for (int i = 0; i < 4; ++i) {
                mn4[i] = fminf(mn4[i], c[i]);
                mx4[i] = fmaxf(mx4[i], c[i]);
            }
        }
    }
    #pragma unroll
    for (int i = 0; i < 4; ++i) {
        float m = mn4[i], M = mx4[i];
        #pragma unroll
        for (int off = 1; off < 16; off <<= 1) {
            m = fminf(m, __shfl_xor(m, off));
            M = fmaxf(M, __shfl_xor(M, off));
        }
        if (lo == 0) {
            rmn[(size_t)bh * NS + s0 + hi * 4 + i] = m;
            rmx[(size_t)bh * NS + s0 + hi * 4 + i] = M;
        }
    }
}

// ---------------- K5a: recompute scores -> sigmoid -> bf16 weights into d_out ----------------
// block = (bh, 64 q-rows), 4 waves; wave w covers t-frags {2w, 2w+1} of each 128-t tile.
__global__ __launch_bounds__(256) void k_weights(
    const unsigned short* __restrict__ qb, const unsigned short* __restrict__ kbf,
    const float* __restrict__ rmn, const float* __restrict__ rmx,
    unsigned short* __restrict__ wgt)
{
    int bid = blockIdx.x;
    int b2 = (bid & 7) * 128 + (bid >> 3);
    int qt = b2 & 15, bh = b2 >> 4;
    int s0 = qt * 64;
    int tid = threadIdx.x;
    int w = tid >> 6, l = tid & 63;
    int lo = l & 15, hi = l >> 4;

    // Q fragments for all 64 q-rows, held in registers
    s8v qa[4][2];
    #pragma unroll
    for (int sub = 0; sub < 4; ++sub) {
        const unsigned short* p = qb + ((size_t)bh * NS + s0 + sub * 16 + lo) * NA + hi * 8;
        qa[sub][0] = ld8(p);
        qa[sub][1] = ld8(p + 32);
    }
    float invv[4][4], n2v[4][4];
    #pragma unroll
    for (int sub = 0; sub < 4; ++sub)
        #pragma unroll
        for (int i = 0; i < 4; ++i) {
            int r = s0 + sub * 16 + hi * 4 + i;
            float mn = rmn[(size_t)bh * NS + r];
            float iv = __builtin_amdgcn_rcpf(rmx[(size_t)bh * NS + r] - mn);
            invv[sub][i] = iv;
            n2v[sub][i] = -mn * iv;
        }

    __shared__ __align__(16) unsigned short Ks[128 * 64];
    const unsigned short* ksrc = kbf + (size_t)bh * NS * NA;
    unsigned short* wrow = wgt + ((size_t)bh * NS + s0) * NS;

    for (int t0 = 0; t0 < NS; t0 += 128) {
        __syncthreads();
        stage_tile(ksrc + (size_t)t0 * NA, NA, 0, Ks, tid);
        __syncthreads();
        #pragma unroll
        for (int j = 0; j < 2; ++j) {
            int tf = w * 2 + j;
            s8v b0 = ld8(Ks + (tf * 16 + lo) * 64 + hi * 8);
            s8v b1 = ld8(Ks + (tf * 16 + lo) * 64 + 32 + hi * 8);
            #pragma unroll
            for (int sub = 0; sub < 4; ++sub) {
                f4v c = {0.f, 0.f, 0.f, 0.f};
                c = MFMA16(qa[sub][0], b0, c);
                c = MFMA16(qa[sub][1], b1, c);
                #pragma unroll
                for (int i = 0; i < 4; ++i) {
                    float sn = fmaf(c[i], invv[sub][i], n2v[sub][i]);
                    float arg = fmaf(sn, -14.4269504089f, 7.2134752044f); // (5-10sn)*log2e
                    float e = __builtin_amdgcn_exp2f(arg);
                    float wv = __builtin_amdgcn_rcpf(1.f + e);
                    wrow[(size_t)(sub * 16 + hi * 4 + i) * NS + t0 + tf * 16 + lo] = f2bf(wv);
                }
            }
        }
    }
}

// ---------------- K5b: PV GEMM: out = W @ V^T ----------------
// block = (bh, 64 q-rows) x FULL e-range; 8 waves, wave w owns e-slice w*64.
// Each block reads exactly the weight-row bytes it later overwrites with f32
// output (wgt aliases d_out): all global W reads complete before the final
// staging barrier, epilogue writes come after -> no intra-block hazard; blocks
// own disjoint 128KB row-bands -> no inter-block sharing.
__global__ __launch_bounds__(512) void k_pv(
    const unsigned short* wgt, const unsigned short* __restrict__ vtb,
    float* out)
{
    int bid = blockIdx.x;                       // 1024
    int b2 = (bid & 7) * 128 + (bid >> 3);      // bijective XCD swizzle
    int qt = b2 & 15, bh = b2 >> 4;
    int s0 = qt * 64;
    int tid = threadIdx.x;
    int w = tid >> 6, l = tid & 63;
    int lo = l & 15, hi = l >> 4;
    int e0 = w * 64;

    __shared__ __align__(16) unsigned short Ws[64 * 128];   // 16 KiB

    const unsigned short* wbase = wgt + ((size_t)bh * NS + s0) * NS;
    const unsigned short* vbase = vtb + ((size_t)bh * NE + e0) * NS;

    f4v acc[4][4];
    f4v z = {0.f, 0.f, 0.f, 0.f};
    #pragma unroll
    for (int i = 0; i < 4; ++i)
        #pragma unroll
        for (int j = 0; j < 4; ++j) acc[i][j] = z;

    int r0 = tid >> 4;          // 0..31
    int cc = tid & 15;          // 16B chunk within 128-ush row

    for (int t0 = 0; t0 < NS; t0 += 128) {
        __syncthreads();        // prev iter's ds_reads done
        #pragma unroll
        for (int p = 0; p < 2; ++p) {
            int r = p * 32 + r0;
            // source column pre-swizzled so linear LDS dest ends up XOR-swizzled
            gload16(wbase + (size_t)r * NS + t0 + ((cc ^ (r & 7)) * 8),
                    Ws + r * 128 + cc * 8);
        }
        __syncthreads();        // staged (vmcnt drained before barrier)
        #pragma unroll
        for (int ks = 0; ks < 4; ++ks) {
            s8v aw[4];
            #pragma unroll
            for (int sub = 0; sub < 4; ++sub) {
                int r = sub * 16 + lo;
                aw[sub] = ld8(Ws + r * 128 + (((ks * 4 + hi) ^ (r & 7)) * 8));
            }
            #pragma unroll
            for (int es = 0; es < 4; ++es) {
                s8v bv = ld8(vbase + (size_t)(es * 16 + lo) * NS + t0 + ks * 32 + hi * 8);
                #pragma unroll
                for (int sub = 0; sub < 4; ++sub)
                    acc[sub][es] = MFMA16(aw[sub], bv, acc[sub][es]);
            }
        }
    }
    #pragma unroll
    for (int sub = 0; sub < 4; ++sub)
        #pragma unroll
        for (int es = 0; es < 4; ++es)
            #pragma unroll
            for (int i = 0; i < 4; ++i)
                out[((size_t)bh * NS + s0 + sub * 16 + hi * 4 + i) * NE
                    + e0 + es * 16 + lo] = acc[sub][es][i];
}

extern "C" void kernel_launch(void* const* d_in, const int* in_sizes, int n_in,
                              void* d_out, int out_size, void* d_ws, size_t ws_size,
                              hipStream_t stream) {
    const int*   x     = (const int*)d_in[0];
    const float* emb   = (const float*)d_in[1];
    const float* gamma = (const float*)d_in[2];
    const float* beta  = (const float*)d_in[3];
    const float* Wq    = (const float*)d_in[4];
    const float* Wk    = (const float*)d_in[5];
    const float* Wv    = (const float*)d_in[6];
    float* out = (float*)d_out;
    unsigned short* wgt = (unsigned short*)d_out;   // 128 MB bf16 scratch, aliases out

    unsigned short* p = (unsigned short*)d_ws;
    unsigned short* hb  = p;  p += (size_t)NB * NS * NE;
    unsigned short* qb  = p;  p += (size_t)NBH * NS * NA;
    unsigned short* kb  = p;  p += (size_t)NBH * NS * NA;
    unsigned short* vtb = p;  p += (size_t)NBH * NS * NE;
    unsigned short* wqb = p;  p += (size_t)NH * NA * NE;
    unsigned short* wkb = p;  p += (size_t)NH * NA * NE;
    unsigned short* wvb = p;  p += (size_t)NH * NE * NE;
    float* rmn = (float*)p;
    float* rmx = rmn + (size_t)NBH * NS;

    const int nqk = NH * NA * NE, nv = NH * NE * NE;
    k_cvt<<<(nqk + 255) / 256, 256, 0, stream>>>(Wq, wqb, nqk);
    k_cvt<<<(nqk + 255) / 256, 256, 0, stream>>>(Wk, wkb, nqk);
    k_cvt<<<(nv + 255) / 256, 256, 0, stream>>>(Wv, wvb, nv);
    k_embed_ln<<<NB * NS, 256, 0, stream>>>(x, emb, gamma, beta, hb);
    k_qk_gemm<<<512, 256, 0, stream>>>(hb, wqb, wkb, qb, kb);
    k_v_gemm<<<2048, 256, 0, stream>>>(hb, wvb, vtb);
    k_minmax_mfma<<<1024, 256, 0, stream>>>(qb, kb, rmn, rmx);
    k_weights<<<1024, 256, 0, stream>>>(qb, kb, rmn, rmx, wgt);
    k_pv<<<1024, 512, 0, stream>>>(wgt, vtb, out);
}